// Round 9
// baseline (125.128 us; speedup 1.0000x reference)
//
#include <hip/hip_runtime.h>
#include <hip/hip_bf16.h>
#include <cstdint>
#include <cstddef>

// ---------------------------------------------------------------------------
// UWBPoseEncoder: B=32, M=2048, T=8, H=64
// prep-weights -> encoder(h1,h2,q,k,v MFMA; LDS-vectorized stores) ->
// flash-attn (32x32 swapped, fixed-reference exp2 softmax, 8-wave blocks,
// split-K pairs, XCD-aware block swizzle) -> a1 MLP -> seg stats ->
// chunked tag_feat partials -> head
// ---------------------------------------------------------------------------

typedef short s16x8 __attribute__((ext_vector_type(8)));
typedef float f32x4 __attribute__((ext_vector_type(4)));
typedef float f32x16 __attribute__((ext_vector_type(16)));

#define LOG2E  1.4426950408889634f
#define QSCALE 0.18033688011112042f   /* 0.125 * log2(e) */

__device__ __forceinline__ unsigned short f2bf(float f) {
    unsigned u = __builtin_bit_cast(unsigned, f);
    u += 0x7fffu + ((u >> 16) & 1u);          // RNE truncate to bf16
    return (unsigned short)(u >> 16);
}

__device__ __forceinline__ unsigned cvtpk(float lo, float hi) {
    unsigned r;
    asm("v_cvt_pk_bf16_f32 %0, %1, %2" : "=v"(r) : "v"(lo), "v"(hi));
    return r;
}

__device__ __forceinline__ float exp2_raw(float x) {
    float r;
    asm("v_exp_f32 %0, %1" : "=v"(r) : "v"(x));
    return r;
}

// swaps upper 32 lanes of a with lower 32 lanes of b
#define PLSWAP(a, b) asm("v_permlane32_swap_b32 %0, %1" : "+v"(a), "+v"(b))

__device__ __forceinline__ void gload_lds16(const void* g, void* l) {
    __builtin_amdgcn_global_load_lds((const __attribute__((address_space(1))) void*)g,
                                     (__attribute__((address_space(3))) void*)l, 16, 0, 0);
}

#define MFMA16(a, b, c) __builtin_amdgcn_mfma_f32_16x16x32_bf16((a), (b), (c), 0, 0, 0)
#define MFMA32(a, b, c) __builtin_amdgcn_mfma_f32_32x32x16_bf16((a), (b), (c), 0, 0, 0)

// ---------------- K0: weight prep (transpose to [out][in], bf16) ------------
__global__ void k_prep(const float* __restrict__ w2, const float* __restrict__ qw,
                       const float* __restrict__ kw, const float* __restrict__ vw,
                       const float* __restrict__ a1w1,
                       unsigned short* __restrict__ wt, float* __restrict__ a1w1t)
{
    int tid = threadIdx.x;
    for (int idx = tid; idx < 4096; idx += 256) {
        int o = idx >> 6, i = idx & 63;
        wt[idx]         = f2bf(w2[i * 64 + o]);
        wt[4096 + idx]  = f2bf(qw[i * 64 + o] * QSCALE);
        wt[8192 + idx]  = f2bf(kw[i * 64 + o]);
        wt[12288 + idx] = f2bf(vw[i * 64 + o]);
    }
    for (int idx = tid; idx < 2048; idx += 256) {
        int j = idx >> 6, d = idx & 63;
        a1w1t[idx] = a1w1[d * 32 + j];
    }
}

// ---------------- K1: encoder + QKV -----------------------------------------
__global__ __launch_bounds__(256)
void k_encode(const float* __restrict__ meas, const float* __restrict__ w1,
              const float* __restrict__ b1, const float* __restrict__ b2,
              const float* __restrict__ qb, const float* __restrict__ kb,
              const float* __restrict__ vb,
              const unsigned short* __restrict__ wt,
              float* __restrict__ feat,
              unsigned short* __restrict__ qbf, unsigned short* __restrict__ kbf,
              unsigned short* __restrict__ vt)
{
    __shared__ __align__(16) unsigned short hbuf[4][1152];   // 16 rows x 72
    int tid = threadIdx.x;
    int w = tid >> 6, lane = tid & 63;
    int g = lane >> 4, c16 = lane & 15;
    int m0 = (blockIdx.x * 4 + w) * 16;          // global row base (b*2048+m)
    int b  = m0 >> 11;
    unsigned short* hb = hbuf[w];
    int vrow = lane >> 2, vseg = lane & 3;       // vectorized-store mapping

    // ---- h1 directly in A-fragment layout ----
    float x[5];
    const float* xr = meas + (size_t)(m0 + c16) * 5;
#pragma unroll
    for (int i = 0; i < 5; ++i) x[i] = xr[i];
    s16x8 aH[2];
#pragma unroll
    for (int s = 0; s < 2; ++s) {
#pragma unroll
        for (int jj = 0; jj < 8; ++jj) {
            int j = 8 * g + jj + 32 * s;
            float acc = b1[j];
#pragma unroll
            for (int i = 0; i < 5; ++i) acc += x[i] * w1[i * 64 + j];
            aH[s][jj] = (short)f2bf(fmaxf(acc, 0.f));
        }
    }

    const f32x4 zero = {0.f, 0.f, 0.f, 0.f};
    f32x4 c[4];

    // ---- h2 = relu(h1 @ W2 + b2) ----
#pragma unroll
    for (int dt = 0; dt < 4; ++dt) {
        c[dt] = zero;
#pragma unroll
        for (int s = 0; s < 2; ++s) {
            s16x8 bf = *(const s16x8*)(wt + (c16 + 16 * dt) * 64 + 32 * s + 8 * g);
            c[dt] = MFMA16(aH[s], bf, c[dt]);
        }
    }
#pragma unroll
    for (int dt = 0; dt < 4; ++dt) {
        int d = c16 + 16 * dt;
        float bias = b2[d];
#pragma unroll
        for (int r = 0; r < 4; ++r) {
            float v = fmaxf(c[dt][r] + bias, 0.f);
            feat[(size_t)(m0 + 4 * g + r) * 64 + d] = v;
            hb[(4 * g + r) * 72 + d] = f2bf(v);
        }
    }
    s16x8 aF[2];
#pragma unroll
    for (int s = 0; s < 2; ++s)
        aF[s] = *(const s16x8*)(hb + c16 * 72 + 32 * s + 8 * g);

    auto gemmW = [&](const unsigned short* wmat, f32x4* cc) {
#pragma unroll
        for (int dt = 0; dt < 4; ++dt) {
            cc[dt] = zero;
#pragma unroll
            for (int s = 0; s < 2; ++s) {
                s16x8 bf = *(const s16x8*)(wmat + (c16 + 16 * dt) * 64 + 32 * s + 8 * g);
                cc[dt] = MFMA16(aF[s], bf, cc[dt]);
            }
        }
    };
    // write C-tile (plus bias) to wave-private LDS, then 2x16B coalesced store
    auto storeV = [&](const float* bias4, unsigned short* dstbase) {
#pragma unroll
        for (int dt = 0; dt < 4; ++dt) {
            int d = c16 + 16 * dt;
#pragma unroll
            for (int r = 0; r < 4; ++r)
                hb[(4 * g + r) * 72 + d] = f2bf(c[dt][r] + bias4[dt]);
        }
        s16x8 o0 = *(const s16x8*)(hb + vrow * 72 + vseg * 16);
        s16x8 o1 = *(const s16x8*)(hb + vrow * 72 + vseg * 16 + 8);
        unsigned short* dst = dstbase + (size_t)(m0 + vrow) * 64 + vseg * 16;
        *(s16x8*)dst = o0;
        *(s16x8*)(dst + 8) = o1;
    };

    float bias4[4];
    // ---- q (pre-scaled) ----
    gemmW(wt + 4096, c);
#pragma unroll
    for (int dt = 0; dt < 4; ++dt) bias4[dt] = qb[c16 + 16 * dt] * QSCALE;
    storeV(bias4, qbf);
    // ---- k ----
    gemmW(wt + 8192, c);
#pragma unroll
    for (int dt = 0; dt < 4; ++dt) bias4[dt] = kb[c16 + 16 * dt];
    storeV(bias4, kbf);
    // ---- v: compute, transpose through LDS, store vt[b][d][m] ----
    gemmW(wt + 12288, c);
#pragma unroll
    for (int dt = 0; dt < 4; ++dt) {
        int d = c16 + 16 * dt;
        float bias = vb[d];
#pragma unroll
        for (int r = 0; r < 4; ++r)
            hb[(4 * g + r) * 72 + d] = f2bf(c[dt][r] + bias);
    }
    unsigned short tvv[16];
#pragma unroll
    for (int mr = 0; mr < 16; ++mr) tvv[mr] = hb[mr * 72 + lane];   // column d=lane
    s16x8 v0, v1;
#pragma unroll
    for (int e2 = 0; e2 < 8; ++e2) { v0[e2] = (short)tvv[e2]; v1[e2] = (short)tvv[8 + e2]; }
    unsigned short* dst = vt + ((size_t)b * 64 + lane) * 2048 + (m0 & 2047);
    *(s16x8*)dst = v0;
    *(s16x8*)(dst + 8) = v1;
}

// ---------------- K2: flash attention (32x32 swapped, split-K pairs) --------
// 512 blocks x 512 thr (8 waves, round-6 proven structure) + XCD swizzle:
// bid=(bid&7)*64+(bid>>3) puts each batch's 16 blocks on ONE XCD's L2.
// Fixed-reference softmax: p = exp2(score) directly.
__global__ __launch_bounds__(512, 4)
void k_attn(const unsigned short* __restrict__ qbf, const unsigned short* __restrict__ kbf,
            const unsigned short* __restrict__ vt, float* __restrict__ feat)
{
    __shared__ __align__(16) char smem[37888];
    // staging: K[2][64][64]bf16 @0 (2x8KB), V[2][64][64]bf16 @16384 (2x8KB)
    // merge (after loop): Om[4][64][36]f32 @0, Ml[4][32]f32 @36864

    int tid = threadIdx.x;
    int w_ = tid >> 6, lane = tid & 63;
    int h = lane >> 5, c32 = lane & 31;
    int jhalf = w_ & 1, tile = w_ >> 1;
    int bid = (int)blockIdx.x;
    bid = (bid & 7) * 64 + (bid >> 3);           // XCD-aware swizzle (bijective, 512%8==0)
    int b = bid >> 4;
    int q0g = (bid & 15) * 128 + tile * 32;
    size_t rowbase = (size_t)b * 2048;

    const unsigned short* kbf_b = kbf + rowbase * 64;
    const unsigned short* vt_b  = vt + (size_t)b * 64 * 2048;

    // Q fragments (B-operand): qf[st] = Q[q=c32][16*st + 8h + i]
    s16x8 qf[4];
    {
        const unsigned short* qp = qbf + (rowbase + q0g + c32) * 64 + 8 * h;
#pragma unroll
        for (int st = 0; st < 4; ++st)
            qf[st] = *(const s16x8*)(qp + 16 * st);
    }

    f32x16 zero16;
#pragma unroll
    for (int i = 0; i < 16; ++i) zero16[i] = 0.f;

    f32x16 o[2];
#pragma unroll
    for (int dt = 0; dt < 2; ++dt)
#pragma unroll
        for (int i = 0; i < 16; ++i) o[dt][i] = 0.f;
    float ll = 0.f;

    // staging source (pre-swizzled global addr -> linear LDS dest)
    int srow = 8 * w_ + (lane >> 3);
    int scol = (lane & 7) ^ (srow & 7);
    const unsigned short* gk0 = kbf_b + (size_t)srow * 64 + scol * 8;
    const unsigned short* gv0 = vt_b + (size_t)srow * 2048 + scol * 8;

    auto stage = [&](int kt, int buf) {
        gload_lds16(gk0 + (size_t)kt * 4096, smem + buf * 8192 + w_ * 1024);
        gload_lds16(gv0 + kt * 64, smem + 16384 + buf * 8192 + w_ * 1024);
    };

    stage(0, 0);
    __syncthreads();

    int swz = c32 & 7;
    int krow = 32 * jhalf + c32;

    for (int kt = 0; kt < 32; ++kt) {
        int cur = kt & 1;
        if (kt + 1 < 32) stage(kt + 1, cur ^ 1);

        const char* Kb = smem + cur * 8192;
        const char* Vb = smem + 16384 + cur * 8192;

        // K fragments + V fragments (V hoisted for latency overlap)
        s16x8 kf[4], vf[2][2];
#pragma unroll
        for (int st = 0; st < 4; ++st)
            kf[st] = *(const s16x8*)(Kb + krow * 128 + (((2 * st + h) ^ swz) * 16));
#pragma unroll
        for (int ks = 0; ks < 2; ++ks)
#pragma unroll
            for (int dt = 0; dt < 2; ++dt)
                vf[ks][dt] = *(const s16x8*)(Vb + (32 * dt + c32) * 128 +
                                             (((4 * jhalf + 2 * ks + h) ^ swz) * 16));

        // S^T = K * Q^T
        __builtin_amdgcn_s_setprio(1);
        f32x16 sc = MFMA32(kf[0], qf[0], zero16);
#pragma unroll
        for (int st = 1; st < 4; ++st)
            sc = MFMA32(kf[st], qf[st], sc);
        __builtin_amdgcn_s_setprio(0);

        // p = exp2(score) directly (fixed reference)
        float p[16];
#pragma unroll
        for (int i = 0; i < 16; ++i) p[i] = exp2_raw(sc[i]);

        // pairwise sum tree
        float s;
        {
            float a0 = p[0] + p[1],  a1 = p[2] + p[3],  a2 = p[4] + p[5],  a3 = p[6] + p[7];
            float a4 = p[8] + p[9],  a5 = p[10] + p[11], a6 = p[12] + p[13], a7 = p[14] + p[15];
            float b0 = a0 + a1, b1 = a2 + a3, b2 = a4 + a5, b3 = a6 + a7;
            s = (b0 + b1) + (b2 + b3);
        }
        {   // cross-half sum via permlane32_swap
            float s1 = s, s2 = s;
            PLSWAP(s1, s2);
            s = s1 + s2;
        }
        ll += s;

        unsigned u[8];
#pragma unroll
        for (int k2 = 0; k2 < 8; ++k2) u[k2] = cvtpk(p[2 * k2], p[2 * k2 + 1]);

        __builtin_amdgcn_s_setprio(1);
#pragma unroll
        for (int ks = 0; ks < 2; ++ks) {
            unsigned a0 = u[4 * ks + 0], b0 = u[4 * ks + 2];
            unsigned a1 = u[4 * ks + 1], b1 = u[4 * ks + 3];
            PLSWAP(a0, b0);
            PLSWAP(a1, b1);
            union { unsigned uu[4]; s16x8 v; } pa;
            pa.uu[0] = a0; pa.uu[1] = a1; pa.uu[2] = b0; pa.uu[3] = b1;
#pragma unroll
            for (int dt = 0; dt < 2; ++dt)
                o[dt] = MFMA32(pa.v, vf[ks][dt], o[dt]);
        }
        __builtin_amdgcn_s_setprio(0);
        __syncthreads();
    }

    // ---- merge split-K pairs (w, w^1) and write feat += O/l ----
    float* Om = (float*)smem;                 // [4][64][36]
    float* Ml = (float*)(smem + 36864);       // [4][32]
    if (jhalf) {
#pragma unroll
        for (int dt = 0; dt < 2; ++dt)
#pragma unroll
            for (int rg = 0; rg < 4; ++rg) {
                f32x4 vv;
#pragma unroll
                for (int r = 0; r < 4; ++r) vv[r] = o[dt][4 * rg + r];
                *(f32x4*)&Om[(tile * 64 + 32 * dt + c32) * 36 + 8 * rg + 4 * h] = vv;
            }
        if (h == 0) Ml[tile * 32 + c32] = ll;
    }
    __syncthreads();
    if (!jhalf) {
        float l1 = Ml[tile * 32 + c32];
        float f = 1.f / (ll + l1);
        float fr[16];
#pragma unroll
        for (int r = 0; r < 16; ++r) {
            int qrow = (r & 3) + 8 * (r >> 2) + 4 * h;
            fr[r] = __shfl(f, qrow);
        }
#pragma unroll
        for (int dt = 0; dt < 2; ++dt)
#pragma unroll
            for (int rg = 0; rg < 4; ++rg) {
                f32x4 pv = *(const f32x4*)&Om[(tile * 64 + 32 * dt + c32) * 36 + 8 * rg + 4 * h];
#pragma unroll
                for (int r = 0; r < 4; ++r) {
                    int rr = 4 * rg + r;
                    int qrow = r + 8 * rg + 4 * h;
                    size_t fi = (rowbase + q0g + qrow) * 64 + 32 * dt + c32;
                    feat[fi] += (o[dt][rr] + pv[r]) * fr[rr];
                }
            }
    }
}

// ---------------- K3: a1 = MLP(feat) per row --------------------------------
__global__ __launch_bounds__(256)
void k_a1(const float* __restrict__ feat, const float* __restrict__ w1t,
          const float* __restrict__ b1, const float* __restrict__ w2,
          const float* __restrict__ b2, float* __restrict__ a1)
{
    int m = blockIdx.x * 256 + threadIdx.x;
    const f32x4* fr = (const f32x4*)(feat + (size_t)m * 64);

    float acc[32];
#pragma unroll
    for (int j = 0; j < 32; ++j) acc[j] = b1[j];

#pragma unroll
    for (int kc = 0; kc < 16; ++kc) {
        f32x4 f = fr[kc];
#pragma unroll
        for (int ki = 0; ki < 4; ++ki) {
            float fk = f[ki];
            int k = kc * 4 + ki;
#pragma unroll
            for (int j = 0; j < 32; ++j)
                acc[j] = fmaf(fk, w1t[j * 64 + k], acc[j]);
        }
    }
    float s = b2[0];
#pragma unroll
    for (int j = 0; j < 32; ++j) s += fmaxf(acc[j], 0.f) * w2[j];
    a1[m] = s;
}

// ---------------- K4a: per-batch per-tag max + exp-sum ----------------------
__global__ __launch_bounds__(256)
void k_seg(const float* __restrict__ a1, const int* __restrict__ map,
           float* __restrict__ segstats)
{
    __shared__ float wred[4][8];
    __shared__ float MXs[8];
    int b = blockIdx.x;
    int tid = threadIdx.x, lane = tid & 63, w = tid >> 6;
    const float* a1b = a1 + b * 2048;
    const int* mp = map + b * 2048;

    float mx[8];
#pragma unroll
    for (int t = 0; t < 8; ++t) mx[t] = -1e9f;
    for (int m = tid; m < 2048; m += 256) {
        float v = a1b[m];
        int tg = mp[m];
#pragma unroll
        for (int t = 0; t < 8; ++t)
            if (tg == t) mx[t] = fmaxf(mx[t], v);
    }
#pragma unroll
    for (int t = 0; t < 8; ++t) {
        float v = mx[t];
        v = fmaxf(v, __shfl_xor(v, 1));  v = fmaxf(v, __shfl_xor(v, 2));
        v = fmaxf(v, __shfl_xor(v, 4));  v = fmaxf(v, __shfl_xor(v, 8));
        v = fmaxf(v, __shfl_xor(v, 16)); v = fmaxf(v, __shfl_xor(v, 32));
        mx[t] = v;
    }
    if (lane == 0) {
#pragma unroll
        for (int t = 0; t < 8; ++t) wred[w][t] = mx[t];
    }
    __syncthreads();
    if (tid < 8) {
        float v = fmaxf(fmaxf(wred[0][tid], wred[1][tid]),
                        fmaxf(wred[2][tid], wred[3][tid]));
        MXs[tid] = v;
        segstats[b * 16 + tid] = v;
    }
    __syncthreads();

    float sm[8];
#pragma unroll
    for (int t = 0; t < 8; ++t) sm[t] = 0.f;
    for (int m = tid; m < 2048; m += 256) {
        float v = a1b[m];
        int tg = mp[m];
        float e = exp2f((v - MXs[tg]) * LOG2E);
#pragma unroll
        for (int t = 0; t < 8; ++t)
            if (tg == t) sm[t] += e;
    }
#pragma unroll
    for (int t = 0; t < 8; ++t) {
        float v = sm[t];
        v += __shfl_xor(v, 1);  v += __shfl_xor(v, 2);
        v += __shfl_xor(v, 4);  v += __shfl_xor(v, 8);
        v += __shfl_xor(v, 16); v += __shfl_xor(v, 32);
        sm[t] = v;
    }
    __syncthreads();
    if (lane == 0) {
#pragma unroll
        for (int t = 0; t < 8; ++t) wred[w][t] = sm[t];
    }
    __syncthreads();
    if (tid < 8)
        segstats[b * 16 + 8 + tid] =
            1.f / (wred[0][tid] + wred[1][tid] + wred[2][tid] + wred[3][tid]);
}

// ---------------- K4b: chunked tag_feat partials ----------------------------
// 512 blocks = 32 batches x 16 chunks of 128 measurements.
__global__ __launch_bounds__(256)
void k_tagfeat(const float* __restrict__ a1, const int* __restrict__ map,
               const float* __restrict__ feat, const float* __restrict__ segstats,
               float* __restrict__ part)
{
    __shared__ float accv[4][8][64];
    __shared__ float MXs[8], SMIs[8];
    int b = blockIdx.x >> 4;
    int c = blockIdx.x & 15;
    int tid = threadIdx.x, lane = tid & 63, w = tid >> 6;

    if (tid < 16) {
        float v = segstats[b * 16 + tid];
        if (tid < 8) MXs[tid] = v; else SMIs[tid - 8] = v;
    }
    __syncthreads();

    const float* a1b = a1 + b * 2048;
    const int* mp = map + b * 2048;
    int m0 = c * 128;

    float tacc[8];
#pragma unroll
    for (int t = 0; t < 8; ++t) tacc[t] = 0.f;
    for (int mi = w; mi < 128; mi += 4) {
        int m = m0 + mi;
        float v = a1b[m];
        int tg = mp[m];
        float wgt = exp2f((v - MXs[tg]) * LOG2E) * SMIs[tg];
        float wf = wgt * feat[((size_t)b * 2048 + m) * 64 + lane];
#pragma unroll
        for (int t = 0; t < 8; ++t)
            if (tg == t) tacc[t] += wf;
    }
#pragma unroll
    for (int t = 0; t < 8; ++t) accv[w][t][lane] = tacc[t];
    __syncthreads();
    for (int e = tid; e < 512; e += 256) {
        int t = e >> 6, d = e & 63;
        part[((size_t)c * 32 + b) * 512 + e] =
            accv[0][t][d] + accv[1][t][d] + accv[2][t][d] + accv[3][t][d];
    }
}

// ---------------- K4c: reduce partials + a2 head + outputs ------------------
__global__ __launch_bounds__(256)
void k_head(const float* __restrict__ part,
            const float* __restrict__ a2w1, const float* __restrict__ a2b1,
            const float* __restrict__ a2w2, const float* __restrict__ a2b2,
            const float* __restrict__ muw, const float* __restrict__ mub,
            const float* __restrict__ lLw, const float* __restrict__ lLb,
            float* __restrict__ out)
{
    __shared__ float tf[8][64];
    __shared__ float sc8[8];
    __shared__ float pose[64];
    int b = blockIdx.x;
    int tid = threadIdx.x;

    for (int e = tid; e < 512; e += 256) {
        float s = 0.f;
#pragma unroll
        for (int c = 0; c < 16; ++c) s += part[((size_t)c * 32 + b) * 512 + e];
        tf[e >> 6][e & 63] = s;
    }
    __syncthreads();

    {
        int t = tid >> 5, j = tid & 31;
        float acc = a2b1[j];
        for (int d = 0; d < 64; ++d) acc += tf[t][d] * a2w1[d * 32 + j];
        float hsum = fmaxf(acc, 0.f) * a2w2[j];
        hsum += __shfl_xor(hsum, 1);
        hsum += __shfl_xor(hsum, 2);
        hsum += __shfl_xor(hsum, 4);
        hsum += __shfl_xor(hsum, 8);
        hsum += __shfl_xor(hsum, 16);
        if (j == 0) sc8[t] = hsum + a2b2[0];
    }
    __syncthreads();
    if (tid < 64) {
        float smax = sc8[0];
#pragma unroll
        for (int t = 1; t < 8; ++t) smax = fmaxf(smax, sc8[t]);
        float e[8], ssum = 0.f;
#pragma unroll
        for (int t = 0; t < 8; ++t) { e[t] = exp2f((sc8[t] - smax) * LOG2E); ssum += e[t]; }
        float rinv = 1.f / ssum;
        float p = 0.f;
#pragma unroll
        for (int t = 0; t < 8; ++t) p += (e[t] * rinv) * tf[t][tid];
        pose[tid] = p;
    }
    __syncthreads();
    if (tid < 3) {
        float acc = mub[tid];
        for (int d = 0; d < 64; ++d) acc += pose[d] * muw[d * 3 + tid];
        out[b * 3 + tid] = acc;
    }
    if (tid >= 32 && tid < 38) {
        int oo = tid - 32;
        float acc = lLb[oo];
        for (int d = 0; d < 64; ++d) acc += pose[d] * lLw[d * 6 + oo];
        out[96 + b * 6 + oo] = acc;
    }
}

// ---------------------------------------------------------------------------
extern "C" void kernel_launch(void* const* d_in, const int* in_sizes, int n_in,
                              void* d_out, int out_size, void* d_ws, size_t ws_size,
                              hipStream_t stream)
{
    (void)in_sizes; (void)n_in; (void)out_size; (void)ws_size;

    const float* measurements = (const float*)d_in[0];
    const int*   mapping      = (const int*)d_in[1];
    const float* me_w1 = (const float*)d_in[2];
    const float* me_b1 = (const float*)d_in[3];
    const float* me_w2 = (const float*)d_in[4];
    const float* me_b2 = (const float*)d_in[5];
    const float* q_w   = (const float*)d_in[6];
    const float* q_b   = (const float*)d_in[7];
    const float* k_w   = (const float*)d_in[8];
    const float* k_b   = (const float*)d_in[9];
    const float* v_w   = (const float*)d_in[10];
    const float* v_b   = (const float*)d_in[11];
    const float* a1_w1 = (const float*)d_in[12];
    const float* a1_b1 = (const float*)d_in[13];
    const float* a1_w2 = (const float*)d_in[14];
    const float* a1_b2 = (const float*)d_in[15];
    const float* a2_w1 = (const float*)d_in[16];
    const float* a2_b1 = (const float*)d_in[17];
    const float* a2_w2 = (const float*)d_in[18];
    const float* a2_b2 = (const float*)d_in[19];
    const float* mu_w  = (const float*)d_in[20];
    const float* mu_b  = (const float*)d_in[21];
    const float* logL_w = (const float*)d_in[22];
    const float* logL_b = (const float*)d_in[23];

    char* ws = (char*)d_ws;
    unsigned short* wt    = (unsigned short*)(ws);                 // 32768 B
    float*          a1w1t = (float*)(ws + 32768);                  //  8192 B
    float*          feat  = (float*)(ws + 40960);                  // 16 MB
    unsigned short* qbf   = (unsigned short*)(ws + 16818176);      // 8 MB
    unsigned short* kbf   = (unsigned short*)(ws + 25206784);      // 8 MB
    unsigned short* vt    = (unsigned short*)(ws + 33595392);      // 8 MB [b][d][m]
    float*          a1    = (float*)(ws + 41984000);               // 256 KB
    float*          segst = (float*)(ws + 42246144);               // 2 KB
    float*          part  = (float*)(ws + 42248192);               // 1 MB
    float*          out   = (float*)d_out;

    k_prep<<<1, 256, 0, stream>>>(me_w2, q_w, k_w, v_w, a1_w1, wt, a1w1t);
    k_encode<<<1024, 256, 0, stream>>>(measurements, me_w1, me_b1, me_b2, q_b, k_b, v_b,
                                       wt, feat, qbf, kbf, vt);
    k_attn<<<512, 512, 0, stream>>>(qbf, kbf, vt, feat);
    k_a1<<<256, 256, 0, stream>>>(feat, a1w1t, a1_b1, a1_w2, a1_b2, a1);
    k_seg<<<32, 256, 0, stream>>>(a1, mapping, segst);
    k_tagfeat<<<512, 256, 0, stream>>>(a1, mapping, feat, segst, part);
    k_head<<<32, 256, 0, stream>>>(part, a2_w1, a2_b1, a2_w2, a2_b2,
                                   mu_w, mu_b, logL_w, logL_b, out);
}

// Round 10
// 110.834 us; speedup vs baseline: 1.1290x; 1.1290x over previous
//
#include <hip/hip_runtime.h>
#include <hip/hip_bf16.h>
#include <cstdint>
#include <cstddef>

// ---------------------------------------------------------------------------
// UWBPoseEncoder: B=32, M=2048, T=8, H=64
// prep-weights -> encoder(h1,h2,q,k,v MFMA) -> flash-attn (32x32 swapped,
// fixed-reference exp2 softmax, XCD swizzle; FROZEN from round 9) ->
// fused a1+segment-partials (fixed-reference, no max pass) -> head
// ---------------------------------------------------------------------------

typedef short s16x8 __attribute__((ext_vector_type(8)));
typedef float f32x4 __attribute__((ext_vector_type(4)));
typedef float f32x16 __attribute__((ext_vector_type(16)));

#define LOG2E  1.4426950408889634f
#define QSCALE 0.18033688011112042f   /* 0.125 * log2(e) */

__device__ __forceinline__ unsigned short f2bf(float f) {
    unsigned u = __builtin_bit_cast(unsigned, f);
    u += 0x7fffu + ((u >> 16) & 1u);          // RNE truncate to bf16
    return (unsigned short)(u >> 16);
}

__device__ __forceinline__ unsigned cvtpk(float lo, float hi) {
    unsigned r;
    asm("v_cvt_pk_bf16_f32 %0, %1, %2" : "=v"(r) : "v"(lo), "v"(hi));
    return r;
}

__device__ __forceinline__ float exp2_raw(float x) {
    float r;
    asm("v_exp_f32 %0, %1" : "=v"(r) : "v"(x));
    return r;
}

// swaps upper 32 lanes of a with lower 32 lanes of b
#define PLSWAP(a, b) asm("v_permlane32_swap_b32 %0, %1" : "+v"(a), "+v"(b))

__device__ __forceinline__ void gload_lds16(const void* g, void* l) {
    __builtin_amdgcn_global_load_lds((const __attribute__((address_space(1))) void*)g,
                                     (__attribute__((address_space(3))) void*)l, 16, 0, 0);
}

#define MFMA16(a, b, c) __builtin_amdgcn_mfma_f32_16x16x32_bf16((a), (b), (c), 0, 0, 0)
#define MFMA32(a, b, c) __builtin_amdgcn_mfma_f32_32x32x16_bf16((a), (b), (c), 0, 0, 0)

// ---------------- K0: weight prep (transpose to [out][in], bf16) ------------
// 8 blocks (was 1: pure serial-latency fix).
__global__ void k_prep(const float* __restrict__ w2, const float* __restrict__ qw,
                       const float* __restrict__ kw, const float* __restrict__ vw,
                       unsigned short* __restrict__ wt)
{
    int tid = blockIdx.x * 256 + threadIdx.x;   // 2048 threads
    for (int idx = tid; idx < 4096; idx += 2048) {
        int o = idx >> 6, i = idx & 63;
        wt[idx]         = f2bf(w2[i * 64 + o]);
        wt[4096 + idx]  = f2bf(qw[i * 64 + o] * QSCALE);
        wt[8192 + idx]  = f2bf(kw[i * 64 + o]);
        wt[12288 + idx] = f2bf(vw[i * 64 + o]);
    }
}

// ---------------- K1: encoder + QKV -----------------------------------------
__global__ __launch_bounds__(256)
void k_encode(const float* __restrict__ meas, const float* __restrict__ w1,
              const float* __restrict__ b1, const float* __restrict__ b2,
              const float* __restrict__ qb, const float* __restrict__ kb,
              const float* __restrict__ vb,
              const unsigned short* __restrict__ wt,
              float* __restrict__ feat,
              unsigned short* __restrict__ qbf, unsigned short* __restrict__ kbf,
              unsigned short* __restrict__ vt)
{
    __shared__ __align__(16) unsigned short hbuf[4][1152];   // 16 rows x 72
    int tid = threadIdx.x;
    int w = tid >> 6, lane = tid & 63;
    int g = lane >> 4, c16 = lane & 15;
    int m0 = (blockIdx.x * 4 + w) * 16;          // global row base (b*2048+m)
    int b  = m0 >> 11;
    unsigned short* hb = hbuf[w];
    int vrow = lane >> 2, vseg = lane & 3;       // vectorized-store mapping

    // ---- h1 directly in A-fragment layout ----
    float x[5];
    const float* xr = meas + (size_t)(m0 + c16) * 5;
#pragma unroll
    for (int i = 0; i < 5; ++i) x[i] = xr[i];
    s16x8 aH[2];
#pragma unroll
    for (int s = 0; s < 2; ++s) {
#pragma unroll
        for (int jj = 0; jj < 8; ++jj) {
            int j = 8 * g + jj + 32 * s;
            float acc = b1[j];
#pragma unroll
            for (int i = 0; i < 5; ++i) acc += x[i] * w1[i * 64 + j];
            aH[s][jj] = (short)f2bf(fmaxf(acc, 0.f));
        }
    }

    const f32x4 zero = {0.f, 0.f, 0.f, 0.f};
    f32x4 c[4];

    // ---- h2 = relu(h1 @ W2 + b2) ----
#pragma unroll
    for (int dt = 0; dt < 4; ++dt) {
        c[dt] = zero;
#pragma unroll
        for (int s = 0; s < 2; ++s) {
            s16x8 bf = *(const s16x8*)(wt + (c16 + 16 * dt) * 64 + 32 * s + 8 * g);
            c[dt] = MFMA16(aH[s], bf, c[dt]);
        }
    }
#pragma unroll
    for (int dt = 0; dt < 4; ++dt) {
        int d = c16 + 16 * dt;
        float bias = b2[d];
#pragma unroll
        for (int r = 0; r < 4; ++r) {
            float v = fmaxf(c[dt][r] + bias, 0.f);
            feat[(size_t)(m0 + 4 * g + r) * 64 + d] = v;
            hb[(4 * g + r) * 72 + d] = f2bf(v);
        }
    }
    s16x8 aF[2];
#pragma unroll
    for (int s = 0; s < 2; ++s)
        aF[s] = *(const s16x8*)(hb + c16 * 72 + 32 * s + 8 * g);

    auto gemmW = [&](const unsigned short* wmat, f32x4* cc) {
#pragma unroll
        for (int dt = 0; dt < 4; ++dt) {
            cc[dt] = zero;
#pragma unroll
            for (int s = 0; s < 2; ++s) {
                s16x8 bf = *(const s16x8*)(wmat + (c16 + 16 * dt) * 64 + 32 * s + 8 * g);
                cc[dt] = MFMA16(aF[s], bf, cc[dt]);
            }
        }
    };
    // write C-tile (plus bias) to wave-private LDS, then 2x16B coalesced store
    auto storeV = [&](const float* bias4, unsigned short* dstbase) {
#pragma unroll
        for (int dt = 0; dt < 4; ++dt) {
            int d = c16 + 16 * dt;
#pragma unroll
            for (int r = 0; r < 4; ++r)
                hb[(4 * g + r) * 72 + d] = f2bf(c[dt][r] + bias4[dt]);
        }
        s16x8 o0 = *(const s16x8*)(hb + vrow * 72 + vseg * 16);
        s16x8 o1 = *(const s16x8*)(hb + vrow * 72 + vseg * 16 + 8);
        unsigned short* dst = dstbase + (size_t)(m0 + vrow) * 64 + vseg * 16;
        *(s16x8*)dst = o0;
        *(s16x8*)(dst + 8) = o1;
    };

    float bias4[4];
    // ---- q (pre-scaled) ----
    gemmW(wt + 4096, c);
#pragma unroll
    for (int dt = 0; dt < 4; ++dt) bias4[dt] = qb[c16 + 16 * dt] * QSCALE;
    storeV(bias4, qbf);
    // ---- k ----
    gemmW(wt + 8192, c);
#pragma unroll
    for (int dt = 0; dt < 4; ++dt) bias4[dt] = kb[c16 + 16 * dt];
    storeV(bias4, kbf);
    // ---- v: compute, transpose through LDS, store vt[b][d][m] ----
    gemmW(wt + 12288, c);
#pragma unroll
    for (int dt = 0; dt < 4; ++dt) {
        int d = c16 + 16 * dt;
        float bias = vb[d];
#pragma unroll
        for (int r = 0; r < 4; ++r)
            hb[(4 * g + r) * 72 + d] = f2bf(c[dt][r] + bias);
    }
    unsigned short tvv[16];
#pragma unroll
    for (int mr = 0; mr < 16; ++mr) tvv[mr] = hb[mr * 72 + lane];   // column d=lane
    s16x8 v0, v1;
#pragma unroll
    for (int e2 = 0; e2 < 8; ++e2) { v0[e2] = (short)tvv[e2]; v1[e2] = (short)tvv[8 + e2]; }
    unsigned short* dst = vt + ((size_t)b * 64 + lane) * 2048 + (m0 & 2047);
    *(s16x8*)dst = v0;
    *(s16x8*)(dst + 8) = v1;
}

// ---------------- K2: flash attention (FROZEN from round 9) -----------------
__global__ __launch_bounds__(512, 4)
void k_attn(const unsigned short* __restrict__ qbf, const unsigned short* __restrict__ kbf,
            const unsigned short* __restrict__ vt, float* __restrict__ feat)
{
    __shared__ __align__(16) char smem[37888];

    int tid = threadIdx.x;
    int w_ = tid >> 6, lane = tid & 63;
    int h = lane >> 5, c32 = lane & 31;
    int jhalf = w_ & 1, tile = w_ >> 1;
    int bid = (int)blockIdx.x;
    bid = (bid & 7) * 64 + (bid >> 3);           // XCD-aware swizzle (bijective)
    int b = bid >> 4;
    int q0g = (bid & 15) * 128 + tile * 32;
    size_t rowbase = (size_t)b * 2048;

    const unsigned short* kbf_b = kbf + rowbase * 64;
    const unsigned short* vt_b  = vt + (size_t)b * 64 * 2048;

    s16x8 qf[4];
    {
        const unsigned short* qp = qbf + (rowbase + q0g + c32) * 64 + 8 * h;
#pragma unroll
        for (int st = 0; st < 4; ++st)
            qf[st] = *(const s16x8*)(qp + 16 * st);
    }

    f32x16 zero16;
#pragma unroll
    for (int i = 0; i < 16; ++i) zero16[i] = 0.f;

    f32x16 o[2];
#pragma unroll
    for (int dt = 0; dt < 2; ++dt)
#pragma unroll
        for (int i = 0; i < 16; ++i) o[dt][i] = 0.f;
    float ll = 0.f;

    int srow = 8 * w_ + (lane >> 3);
    int scol = (lane & 7) ^ (srow & 7);
    const unsigned short* gk0 = kbf_b + (size_t)srow * 64 + scol * 8;
    const unsigned short* gv0 = vt_b + (size_t)srow * 2048 + scol * 8;

    auto stage = [&](int kt, int buf) {
        gload_lds16(gk0 + (size_t)kt * 4096, smem + buf * 8192 + w_ * 1024);
        gload_lds16(gv0 + kt * 64, smem + 16384 + buf * 8192 + w_ * 1024);
    };

    stage(0, 0);
    __syncthreads();

    int swz = c32 & 7;
    int krow = 32 * jhalf + c32;

    for (int kt = 0; kt < 32; ++kt) {
        int cur = kt & 1;
        if (kt + 1 < 32) stage(kt + 1, cur ^ 1);

        const char* Kb = smem + cur * 8192;
        const char* Vb = smem + 16384 + cur * 8192;

        s16x8 kf[4], vf[2][2];
#pragma unroll
        for (int st = 0; st < 4; ++st)
            kf[st] = *(const s16x8*)(Kb + krow * 128 + (((2 * st + h) ^ swz) * 16));
#pragma unroll
        for (int ks = 0; ks < 2; ++ks)
#pragma unroll
            for (int dt = 0; dt < 2; ++dt)
                vf[ks][dt] = *(const s16x8*)(Vb + (32 * dt + c32) * 128 +
                                             (((4 * jhalf + 2 * ks + h) ^ swz) * 16));

        __builtin_amdgcn_s_setprio(1);
        f32x16 sc = MFMA32(kf[0], qf[0], zero16);
#pragma unroll
        for (int st = 1; st < 4; ++st)
            sc = MFMA32(kf[st], qf[st], sc);
        __builtin_amdgcn_s_setprio(0);

        float p[16];
#pragma unroll
        for (int i = 0; i < 16; ++i) p[i] = exp2_raw(sc[i]);

        float s;
        {
            float a0 = p[0] + p[1],  a1 = p[2] + p[3],  a2 = p[4] + p[5],  a3 = p[6] + p[7];
            float a4 = p[8] + p[9],  a5 = p[10] + p[11], a6 = p[12] + p[13], a7 = p[14] + p[15];
            float b0 = a0 + a1, b1 = a2 + a3, b2 = a4 + a5, b3 = a6 + a7;
            s = (b0 + b1) + (b2 + b3);
        }
        {
            float s1 = s, s2 = s;
            PLSWAP(s1, s2);
            s = s1 + s2;
        }
        ll += s;

        unsigned u[8];
#pragma unroll
        for (int k2 = 0; k2 < 8; ++k2) u[k2] = cvtpk(p[2 * k2], p[2 * k2 + 1]);

        __builtin_amdgcn_s_setprio(1);
#pragma unroll
        for (int ks = 0; ks < 2; ++ks) {
            unsigned a0 = u[4 * ks + 0], b0 = u[4 * ks + 2];
            unsigned a1 = u[4 * ks + 1], b1 = u[4 * ks + 3];
            PLSWAP(a0, b0);
            PLSWAP(a1, b1);
            union { unsigned uu[4]; s16x8 v; } pa;
            pa.uu[0] = a0; pa.uu[1] = a1; pa.uu[2] = b0; pa.uu[3] = b1;
#pragma unroll
            for (int dt = 0; dt < 2; ++dt)
                o[dt] = MFMA32(pa.v, vf[ks][dt], o[dt]);
        }
        __builtin_amdgcn_s_setprio(0);
        __syncthreads();
    }

    float* Om = (float*)smem;                 // [4][64][36]
    float* Ml = (float*)(smem + 36864);       // [4][32]
    if (jhalf) {
#pragma unroll
        for (int dt = 0; dt < 2; ++dt)
#pragma unroll
            for (int rg = 0; rg < 4; ++rg) {
                f32x4 vv;
#pragma unroll
                for (int r = 0; r < 4; ++r) vv[r] = o[dt][4 * rg + r];
                *(f32x4*)&Om[(tile * 64 + 32 * dt + c32) * 36 + 8 * rg + 4 * h] = vv;
            }
        if (h == 0) Ml[tile * 32 + c32] = ll;
    }
    __syncthreads();
    if (!jhalf) {
        float l1 = Ml[tile * 32 + c32];
        float f = 1.f / (ll + l1);
        float fr[16];
#pragma unroll
        for (int r = 0; r < 16; ++r) {
            int qrow = (r & 3) + 8 * (r >> 2) + 4 * h;
            fr[r] = __shfl(f, qrow);
        }
#pragma unroll
        for (int dt = 0; dt < 2; ++dt)
#pragma unroll
            for (int rg = 0; rg < 4; ++rg) {
                f32x4 pv = *(const f32x4*)&Om[(tile * 64 + 32 * dt + c32) * 36 + 8 * rg + 4 * h];
#pragma unroll
                for (int r = 0; r < 4; ++r) {
                    int rr = 4 * rg + r;
                    int qrow = r + 8 * rg + 4 * h;
                    size_t fi = (rowbase + q0g + qrow) * 64 + 32 * dt + c32;
                    feat[fi] += (o[dt][rr] + pv[r]) * fr[rr];
                }
            }
    }
}

// ---------------- K3: fused a1 MLP + unnormalized tag partials --------------
// 512 blocks = 32 batches x 16 chunks of 128 rows. Fixed-reference segment
// softmax: e = exp2(a1*log2e) directly (scale-free ratios; |a1| small).
__global__ __launch_bounds__(256)
void k_a1tag(const float* __restrict__ feat, const int* __restrict__ map,
             const float* __restrict__ a1w1, const float* __restrict__ b1,
             const float* __restrict__ w2, const float* __restrict__ b2,
             float* __restrict__ part1, float* __restrict__ part0)
{
    __shared__ float psum[128][33];
    __shared__ float es[128];
    __shared__ float accv[4][8][64];
    __shared__ float s0red[4][8];

    int b = blockIdx.x >> 4;
    int c = blockIdx.x & 15;
    int tid = threadIdx.x, lane = tid & 63, w = tid >> 6;
    int m0 = c * 128;
    const int* mp = map + b * 2048 + m0;
    const float* fbase = feat + ((size_t)b * 2048 + m0) * 64;

    // phase A: a1 for 128 rows, k-split across thread halves (kh = 0/1)
    {
        int r = tid & 127, kh = tid >> 7;
        const float* fr = fbase + (size_t)r * 64 + kh * 32;
        float acc[32];
#pragma unroll
        for (int j = 0; j < 32; ++j) acc[j] = kh ? 0.f : b1[j];
#pragma unroll
        for (int kk = 0; kk < 32; ++kk) {
            float fv = fr[kk];
            const float* wr = a1w1 + (kh * 32 + kk) * 32;   // [k][j], wave-uniform
#pragma unroll
            for (int j = 0; j < 32; ++j)
                acc[j] = fmaf(fv, wr[j], acc[j]);
        }
        if (kh) {
#pragma unroll
            for (int j = 0; j < 32; ++j) psum[r][j] = acc[j];
        }
        __syncthreads();
        if (!kh) {
            float s = b2[0];
#pragma unroll
            for (int j = 0; j < 32; ++j)
                s += fmaxf(acc[j] + psum[r][j], 0.f) * w2[j];
            es[r] = exp2_raw(s * LOG2E);
        }
    }
    __syncthreads();

    // phase B: unnormalized weighted-feat partials per tag
    float tacc[8], s0t[8];
#pragma unroll
    for (int t = 0; t < 8; ++t) { tacc[t] = 0.f; s0t[t] = 0.f; }
    for (int mi = w; mi < 128; mi += 4) {
        int tg = mp[mi];
        float e = es[mi];
        float wf = e * fbase[(size_t)mi * 64 + lane];
#pragma unroll
        for (int t = 0; t < 8; ++t)
            if (tg == t) { tacc[t] += wf; s0t[t] += e; }
    }
#pragma unroll
    for (int t = 0; t < 8; ++t) accv[w][t][lane] = tacc[t];
    if (lane == 0) {
#pragma unroll
        for (int t = 0; t < 8; ++t) s0red[w][t] = s0t[t];
    }
    __syncthreads();
    for (int e = tid; e < 512; e += 256) {
        int t = e >> 6, d = e & 63;
        part1[((size_t)c * 32 + b) * 512 + e] =
            accv[0][t][d] + accv[1][t][d] + accv[2][t][d] + accv[3][t][d];
    }
    if (tid < 8)
        part0[((size_t)c * 32 + b) * 8 + tid] =
            s0red[0][tid] + s0red[1][tid] + s0red[2][tid] + s0red[3][tid];
}

// ---------------- K4: reduce partials + a2 head + outputs -------------------
__global__ __launch_bounds__(256)
void k_head(const float* __restrict__ part1, const float* __restrict__ part0,
            const float* __restrict__ a2w1, const float* __restrict__ a2b1,
            const float* __restrict__ a2w2, const float* __restrict__ a2b2,
            const float* __restrict__ muw, const float* __restrict__ mub,
            const float* __restrict__ lLw, const float* __restrict__ lLb,
            float* __restrict__ out)
{
    __shared__ float tf[8][64];
    __shared__ float deni[8];
    __shared__ float sc8[8];
    __shared__ float pose[64];
    int b = blockIdx.x;
    int tid = threadIdx.x;

    if (tid < 8) {
        float s = 0.f;
#pragma unroll
        for (int c = 0; c < 16; ++c) s += part0[((size_t)c * 32 + b) * 8 + tid];
        deni[tid] = 1.f / s;
    }
    __syncthreads();
    for (int e = tid; e < 512; e += 256) {
        float s = 0.f;
#pragma unroll
        for (int c = 0; c < 16; ++c) s += part1[((size_t)c * 32 + b) * 512 + e];
        tf[e >> 6][e & 63] = s * deni[e >> 6];
    }
    __syncthreads();

    {
        int t = tid >> 5, j = tid & 31;
        float acc = a2b1[j];
        for (int d = 0; d < 64; ++d) acc += tf[t][d] * a2w1[d * 32 + j];
        float hsum = fmaxf(acc, 0.f) * a2w2[j];
        hsum += __shfl_xor(hsum, 1);
        hsum += __shfl_xor(hsum, 2);
        hsum += __shfl_xor(hsum, 4);
        hsum += __shfl_xor(hsum, 8);
        hsum += __shfl_xor(hsum, 16);
        if (j == 0) sc8[t] = hsum + a2b2[0];
    }
    __syncthreads();
    if (tid < 64) {
        float smax = sc8[0];
#pragma unroll
        for (int t = 1; t < 8; ++t) smax = fmaxf(smax, sc8[t]);
        float e[8], ssum = 0.f;
#pragma unroll
        for (int t = 0; t < 8; ++t) { e[t] = exp2f((sc8[t] - smax) * LOG2E); ssum += e[t]; }
        float rinv = 1.f / ssum;
        float p = 0.f;
#pragma unroll
        for (int t = 0; t < 8; ++t) p += (e[t] * rinv) * tf[t][tid];
        pose[tid] = p;
    }
    __syncthreads();
    if (tid < 3) {
        float acc = mub[tid];
        for (int d = 0; d < 64; ++d) acc += pose[d] * muw[d * 3 + tid];
        out[b * 3 + tid] = acc;
    }
    if (tid >= 32 && tid < 38) {
        int oo = tid - 32;
        float acc = lLb[oo];
        for (int d = 0; d < 64; ++d) acc += pose[d] * lLw[d * 6 + oo];
        out[96 + b * 6 + oo] = acc;
    }
}

// ---------------------------------------------------------------------------
extern "C" void kernel_launch(void* const* d_in, const int* in_sizes, int n_in,
                              void* d_out, int out_size, void* d_ws, size_t ws_size,
                              hipStream_t stream)
{
    (void)in_sizes; (void)n_in; (void)out_size; (void)ws_size;

    const float* measurements = (const float*)d_in[0];
    const int*   mapping      = (const int*)d_in[1];
    const float* me_w1 = (const float*)d_in[2];
    const float* me_b1 = (const float*)d_in[3];
    const float* me_w2 = (const float*)d_in[4];
    const float* me_b2 = (const float*)d_in[5];
    const float* q_w   = (const float*)d_in[6];
    const float* q_b   = (const float*)d_in[7];
    const float* k_w   = (const float*)d_in[8];
    const float* k_b   = (const float*)d_in[9];
    const float* v_w   = (const float*)d_in[10];
    const float* v_b   = (const float*)d_in[11];
    const float* a1_w1 = (const float*)d_in[12];
    const float* a1_b1 = (const float*)d_in[13];
    const float* a1_w2 = (const float*)d_in[14];
    const float* a1_b2 = (const float*)d_in[15];
    const float* a2_w1 = (const float*)d_in[16];
    const float* a2_b1 = (const float*)d_in[17];
    const float* a2_w2 = (const float*)d_in[18];
    const float* a2_b2 = (const float*)d_in[19];
    const float* mu_w  = (const float*)d_in[20];
    const float* mu_b  = (const float*)d_in[21];
    const float* logL_w = (const float*)d_in[22];
    const float* logL_b = (const float*)d_in[23];

    char* ws = (char*)d_ws;
    unsigned short* wt    = (unsigned short*)(ws);                 // 32768 B
    float*          feat  = (float*)(ws + 40960);                  // 16 MB
    unsigned short* qbf   = (unsigned short*)(ws + 16818176);      // 8 MB
    unsigned short* kbf   = (unsigned short*)(ws + 25206784);      // 8 MB
    unsigned short* vt    = (unsigned short*)(ws + 33595392);      // 8 MB [b][d][m]
    float*          part1 = (float*)(ws + 42248192);               // 1 MB
    float*          part0 = (float*)(ws + 43296768);               // 16 KB
    float*          out   = (float*)d_out;

    k_prep<<<8, 256, 0, stream>>>(me_w2, q_w, k_w, v_w, wt);
    k_encode<<<1024, 256, 0, stream>>>(measurements, me_w1, me_b1, me_b2, q_b, k_b, v_b,
                                       wt, feat, qbf, kbf, vt);
    k_attn<<<512, 512, 0, stream>>>(qbf, kbf, vt, feat);
    k_a1tag<<<512, 256, 0, stream>>>(feat, mapping, a1_w1, a1_b1, a1_w2, a1_b2,
                                     part1, part0);
    k_head<<<32, 256, 0, stream>>>(part1, part0, a2_w1, a2_b1, a2_w2, a2_b2,
                                   mu_w, mu_b, logL_w, logL_b, out);
}